// Round 23
// baseline (790.922 us; speedup 1.0000x reference)
//
#include <hip/hip_runtime.h>

#define NPTS 8192
#define NB 2

typedef __attribute__((ext_vector_type(8))) short short8v;   // 8 bf16 (4 VGPRs)
typedef __attribute__((ext_vector_type(4))) float f32x4;

__device__ __forceinline__ float lrelu(float x) { return x > 0.f ? x : 0.2f * x; }
__device__ __forceinline__ float4 lrelu4(float4 a) {
    return make_float4(lrelu(a.x), lrelu(a.y), lrelu(a.z), lrelu(a.w));
}
__device__ __forceinline__ float4 fmax4(float4 a, float4 b) {
    return make_float4(fmaxf(a.x, b.x), fmaxf(a.y, b.y), fmaxf(a.z, b.z), fmaxf(a.w, b.w));
}
__device__ __forceinline__ float4 add4(float4 a, float4 b) {
    return make_float4(a.x + b.x, a.y + b.y, a.z + b.z, a.w + b.w);
}
__device__ __forceinline__ unsigned short f2bf(float f) {     // RNE bf16
    unsigned int u = __float_as_uint(f);
    return (unsigned short)((u + 0x7FFFu + ((u >> 16) & 1u)) >> 16);
}
__device__ __forceinline__ float bf2f(unsigned short h) {
    return __uint_as_float(((unsigned int)h) << 16);
}

// ---------------- prep: transpose layer-2 weights into ws (WbT[c][o]) ----------------
__global__ void k_transpose_w(const float* __restrict__ Wb0, const float* __restrict__ Wb1,
                              float* __restrict__ out) {
    int t = blockIdx.x * 256 + threadIdx.x;
    if (t < 16384)      out[t] = Wb0[(t & 127) * 128 + (t >> 7)];
    else if (t < 32768) { int i = t - 16384; out[t] = Wb1[(i & 127) * 128 + (i >> 7)]; }
}

// 3-way bf16 split of a float4, packed into 2 uints per level
__device__ __forceinline__ void split3(float4 v, unsigned int* hp, unsigned int* mp,
                                       unsigned int* lp) {
    float c[4] = {v.x, v.y, v.z, v.w};
    unsigned short h[4], m[4], l[4];
    #pragma unroll
    for (int i = 0; i < 4; ++i) {
        h[i] = f2bf(c[i]);
        float r1 = c[i] - bf2f(h[i]);
        m[i] = f2bf(r1);
        float r2 = r1 - bf2f(m[i]);
        l[i] = f2bf(r2);
    }
    hp[0] = (unsigned int)h[0] | ((unsigned int)h[1] << 16);
    hp[1] = (unsigned int)h[2] | ((unsigned int)h[3] << 16);
    mp[0] = (unsigned int)m[0] | ((unsigned int)m[1] << 16);
    mp[1] = (unsigned int)m[2] | ((unsigned int)m[3] << 16);
    lp[0] = (unsigned int)l[0] | ((unsigned int)l[1] << 16);
    lp[1] = (unsigned int)l[2] | ((unsigned int)l[3] << 16);
}

// ---------------- conv_in: feature -> x0 fp32 + sq0 + bf16 h/m/l split ----------------
__global__ void k_conv_in(const float* __restrict__ f, const float* __restrict__ W,
                          const float* __restrict__ bias, float* __restrict__ out,
                          float* __restrict__ sq, unsigned short* __restrict__ xh,
                          unsigned short* __restrict__ xm, unsigned short* __restrict__ xl) {
    int gid = blockIdx.x * blockDim.x + threadIdx.x;   // over B*N
    int b = gid >> 13, n = gid & (NPTS - 1);
    const float* fb = f + ((size_t)b << 20) + n;       // b*128*8192
    float acc[32];
    #pragma unroll
    for (int o = 0; o < 32; ++o) acc[o] = bias[o];
    #pragma unroll 4
    for (int c = 0; c < 128; ++c) {
        float xc = fb[(size_t)c * NPTS];               // coalesced across lanes
        #pragma unroll
        for (int o = 0; o < 32; ++o) acc[o] += xc * W[o * 128 + c];  // uniform -> s_load
    }
    float s = 0.f;
    float4* op = (float4*)(out + (size_t)gid * 32);
    unsigned int* hrow = (unsigned int*)(xh + (size_t)gid * 32);
    unsigned int* mrow = (unsigned int*)(xm + (size_t)gid * 32);
    unsigned int* lrow = (unsigned int*)(xl + (size_t)gid * 32);
    #pragma unroll
    for (int o4 = 0; o4 < 8; ++o4) {
        float4 v = make_float4(lrelu(acc[o4 * 4]), lrelu(acc[o4 * 4 + 1]),
                               lrelu(acc[o4 * 4 + 2]), lrelu(acc[o4 * 4 + 3]));
        s += v.x * v.x + v.y * v.y + v.z * v.z + v.w * v.w;
        op[o4] = v;
        unsigned int hp[2], mp[2], lp[2];
        split3(v, hp, mp, lp);
        *(uint2*)(hrow + o4 * 2) = make_uint2(hp[0], hp[1]);
        *(uint2*)(mrow + o4 * 2) = make_uint2(mp[0], mp[1]);
        *(uint2*)(lrow + o4 * 2) = make_uint2(lp[0], lp[1]);
    }
    sq[gid] = s;
}

// ---------------- premix: A = x @ Wa1^T ; Bm = x @ (Wa2-Wa1)^T + ba ----------------
// (256,2): 128-VGPR budget so xv[8]+acc[32] stay in registers (R19 fix).
__global__ __launch_bounds__(256, 2) void k_premix(const float* __restrict__ x,
                                                   const float* __restrict__ Wa,
                                                   const float* __restrict__ ba,
                                                   float* __restrict__ A,
                                                   float* __restrict__ Bm) {
    int tid = threadIdx.x;
    int q = tid >> 6;                       // quarter (wave-uniform)
    int p = blockIdx.x * 64 + (tid & 63);   // point over NB*NPTS
    float4 xv[8];
    {
        const float4* xr = (const float4*)(x + (size_t)p * 32);
        #pragma unroll
        for (int u = 0; u < 8; ++u) xv[u] = xr[u];
    }
    const float* W0 = Wa + q * 32 * 64;     // rows q*32..q*32+31
    float acc[32];
    #pragma unroll
    for (int o = 0; o < 32; ++o) acc[o] = 0.f;
    #pragma unroll 2
    for (int c4 = 0; c4 < 8; ++c4) {
        float4 v = xv[c4];
        #pragma unroll
        for (int o = 0; o < 32; ++o) {
            const float* w = W0 + o * 64 + c4 * 4;   // uniform -> s_load
            acc[o] += v.x * w[0] + v.y * w[1] + v.z * w[2] + v.w * w[3];
        }
    }
    {
        float4* op = (float4*)(A + (size_t)p * 128 + q * 32);
        #pragma unroll
        for (int o4 = 0; o4 < 8; ++o4)
            op[o4] = make_float4(acc[o4 * 4], acc[o4 * 4 + 1], acc[o4 * 4 + 2], acc[o4 * 4 + 3]);
    }
    #pragma unroll
    for (int o = 0; o < 32; ++o) acc[o] = ba[q * 32 + o];
    #pragma unroll 2
    for (int c4 = 0; c4 < 8; ++c4) {
        float4 v = xv[c4];
        #pragma unroll
        for (int o = 0; o < 32; ++o) {
            const float* w1 = W0 + o * 64 + c4 * 4;
            const float* w2 = w1 + 32;
            acc[o] += v.x * (w2[0] - w1[0]) + v.y * (w2[1] - w1[1]) +
                      v.z * (w2[2] - w1[2]) + v.w * (w2[3] - w1[3]);
        }
    }
    {
        float4* op = (float4*)(Bm + (size_t)p * 128 + q * 32);
        #pragma unroll
        for (int o4 = 0; o4 < 8; ++o4)
            op[o4] = make_float4(acc[o4 * 4], acc[o4 * 4 + 1], acc[o4 * 4 + 2], acc[o4 * 4 + 3]);
    }
}

// ---------------- kNN via MFMA Gram (bf16 3-way split, 6 terms), BARRIER-FREE ----------------
// JS=16: 2048 blocks -> ~8 blocks/CU -> ~4 waves/SIMD (R22 lesson: total waves =
// points*JS/64 regardless of tiling; JS is the only occupancy lever).
template <int K, int JS, int C>
__global__ __launch_bounds__(128, 2) void k_knn_mfma(const unsigned short* __restrict__ xh,
                                                     const unsigned short* __restrict__ xm,
                                                     const unsigned short* __restrict__ xl,
                                                     const float* __restrict__ sqg,
                                                     float* __restrict__ cand_d,
                                                     int* __restrict__ cand_i) {
    constexpr int IT = 128;                  // i-tile
    constexpr int JR = NPTS / JS;            // 512 for JS=16
    constexpr int NCH = JR / 16;             // chunks of 16 j
    constexpr int BPB = (NPTS / IT) * JS;    // blocks per batch
    constexpr int DS = 17;                   // Dl row stride (reads 2-way free)

    __shared__ float Dl[IT * DS];
    __shared__ float bufd[C * IT];           // transposed append buffer (conflict-free)
    __shared__ int   bufj[C * IT];

    int tid = threadIdx.x;
    int bid = blockIdx.x;
    int b = bid / BPB;
    int r0b = bid - b * BPB;
    int itile = r0b / JS;
    int jseg = r0b - itile * JS;

    const unsigned short* xhb = xh + ((size_t)b * NPTS) * 32;
    const unsigned short* xmb = xm + ((size_t)b * NPTS) * 32;
    const unsigned short* xlb = xl + ((size_t)b * NPTS) * 32;
    const float* sqb = sqg + (size_t)b * NPTS;

    int lane = tid & 63;
    int w = tid >> 6;          // wave 0..1 -> i rows [w*64, w*64+64)
    int g = lane >> 4;         // k-group: k = g*8 + e
    int r15 = lane & 15;

    // A fragments hoisted and pinned
    short8v ah[4], am[4], al[4];
    #pragma unroll
    for (int t = 0; t < 4; ++t) {
        size_t ii = (size_t)(itile * IT + w * 64 + t * 16 + r15);
        ah[t] = *(const short8v*)(xhb + ii * 32 + g * 8);
        am[t] = *(const short8v*)(xmb + ii * 32 + g * 8);
        al[t] = *(const short8v*)(xlb + ii * 32 + g * 8);
    }
    #pragma unroll
    for (int t = 0; t < 4; ++t) {
        asm volatile("" : "+v"(ah[t]));
        asm volatile("" : "+v"(am[t]));
        asm volatile("" : "+v"(al[t]));
    }

    float bd[K]; int bi[K];                  // sorted ascending, registers
    #pragma unroll
    for (int r = 0; r < K; ++r) { bd[r] = 1e30f; bi[r] = 0; }
    float thr = 1e30f;
    int cnt = 0;

    auto flush = [&]() {
        #pragma unroll
        for (int u = 0; u < C; ++u) {
            float dv = bufd[u * IT + tid];
            int jv = bufj[u * IT + tid];
            float dd = (u < cnt) ? dv : 1e30f;   // 1e30 never inserts (strict <)
            int ji = jv;
            #pragma unroll
            for (int r = 0; r < K; ++r) {
                bool c = dd < bd[r];
                float tf = bd[r]; int ti = bi[r];
                bd[r] = c ? dd : bd[r]; bi[r] = c ? ji : bi[r];
                dd = c ? tf : dd;       ji = c ? ti : ji;
            }
        }
        cnt = 0; thr = bd[K - 1];
    };

    int jbase = jseg * JR;
    #pragma unroll 1
    for (int ch = 0; ch < NCH; ++ch) {
        int j0 = jbase + ch * 16;
        // B fragments for this 16-j chunk (3 levels)
        short8v bh, bm, bl;
        {
            size_t ja = (size_t)(j0 + r15);
            bh = *(const short8v*)(xhb + ja * 32 + g * 8);
            bm = *(const short8v*)(xmb + ja * 32 + g * 8);
            bl = *(const short8v*)(xlb + ja * 32 + g * 8);
        }
        #pragma unroll
        for (int t = 0; t < 4; ++t) {
            f32x4 acc = {0.f, 0.f, 0.f, 0.f};
            acc = __builtin_amdgcn_mfma_f32_16x16x32_bf16(am[t], bm, acc, 0, 0, 0);
            acc = __builtin_amdgcn_mfma_f32_16x16x32_bf16(ah[t], bl, acc, 0, 0, 0);
            acc = __builtin_amdgcn_mfma_f32_16x16x32_bf16(al[t], bh, acc, 0, 0, 0);
            acc = __builtin_amdgcn_mfma_f32_16x16x32_bf16(ah[t], bm, acc, 0, 0, 0);
            acc = __builtin_amdgcn_mfma_f32_16x16x32_bf16(am[t], bh, acc, 0, 0, 0);
            acc = __builtin_amdgcn_mfma_f32_16x16x32_bf16(ah[t], bh, acc, 0, 0, 0);
            int il = w * 64 + t * 16 + g * 4;
            Dl[(il + 0) * DS + r15] = acc[0];
            Dl[(il + 1) * DS + r15] = acc[1];
            Dl[(il + 2) * DS + r15] = acc[2];
            Dl[(il + 3) * DS + r15] = acc[3];
        }
        // selection (wave-private Dl rows; intra-wave lgkmcnt ordering suffices).
        #pragma unroll 1
        for (int jq = 0; jq < 16; jq += 4) {
            float v0 = Dl[tid * DS + jq + 0];
            float v1 = Dl[tid * DS + jq + 1];
            float v2 = Dl[tid * DS + jq + 2];
            float v3 = Dl[tid * DS + jq + 3];
            int j = j0 + jq;
            float d0 = sqb[j + 0] - 2.f * v0;   // rank key (sq_i const offset per i)
            float d1 = sqb[j + 1] - 2.f * v1;
            float d2 = sqb[j + 2] - 2.f * v2;
            float d3 = sqb[j + 3] - 2.f * v3;
            // strict < : on distance tie the earlier (lower-index) j stays -> jax tie-break
            if (d0 < thr) { bufd[cnt * IT + tid] = d0; bufj[cnt * IT + tid] = j + 0; cnt++; }
            if (d1 < thr) { bufd[cnt * IT + tid] = d1; bufj[cnt * IT + tid] = j + 1; cnt++; }
            if (d2 < thr) { bufd[cnt * IT + tid] = d2; bufj[cnt * IT + tid] = j + 2; cnt++; }
            if (d3 < thr) { bufd[cnt * IT + tid] = d3; bufj[cnt * IT + tid] = j + 3; cnt++; }
            if (__any(cnt >= C - 3)) flush();   // capacity: cnt <= C-4 at group top
        }
    }
    flush();
    size_t base = ((size_t)jseg * (NB * NPTS) + (size_t)(b * NPTS) + itile * IT + tid) * K;
    #pragma unroll
    for (int r = 0; r < K; ++r) { cand_d[base + r] = bd[r]; cand_i[base + r] = bi[r]; }
}

// ---------------- merge JS candidate lists -> final idx [B*N, K] ----------------
template <int K, int JS>
__global__ void k_knn_merge(const float* __restrict__ cand_d, const int* __restrict__ cand_i,
                            int* __restrict__ idx_out) {
    constexpr int M = JS * K;               // 192 / 64
    __shared__ float md[64 * (M + 1)];
    __shared__ int   mi[64 * (M + 1)];
    int tid = threadIdx.x;                  // 64 threads
    int pbase = blockIdx.x * 64;
    for (int v = tid; v < 64 * M; v += 64) {
        int s = v / (64 * K);
        int rem = v - s * 64 * K;
        int p = rem / K;
        size_t g = ((size_t)s * (NB * NPTS) + pbase + p) * K + (rem - p * K);
        md[p * (M + 1) + s * K + (rem - p * K)] = cand_d[g];
        mi[p * (M + 1) + s * K + (rem - p * K)] = cand_i[g];
    }
    __syncthreads();
    float* rd = md + tid * (M + 1);
    int* ri = mi + tid * (M + 1);
    int* op = idx_out + (size_t)(pbase + tid) * K;
    for (int r = 0; r < K; ++r) {
        float best = 1e30f; int bj = 0x7fffffff; int bs = 0;
        for (int u = 0; u < M; ++u) {
            float dv = rd[u]; int jv = ri[u];
            if (dv < best || (dv == best && jv < bj)) { best = dv; bj = jv; bs = u; }
        }
        rd[bs] = 1e30f;
        op[r] = bj;
    }
}

// ---------------- EdgeConv v4: register-lean 6x8 / 4x8 output tiles ----------------
template <int K>
__global__ __launch_bounds__(256, 1)
void k_edgeconv4(const int* __restrict__ idx,
                 const float* __restrict__ A, const float* __restrict__ Bm,
                 const float* __restrict__ WbTg, const float* __restrict__ bb,
                 float* __restrict__ y) {
    constexpr int TE = (K == 12) ? 6 : 4;     // edges per thread
    constexpr int EPI = 16 * TE;              // edges per iter: 96 / 64
    constexpr int PI = EPI / K;               // points per iter: 8 / 16
    constexpr int ITERS = 64 / PI;            // 8 / 4
    constexpr int NT = 256;
    constexpr int HS = 132;                   // H1 row stride

    __shared__ __align__(16) float WbT[128 * 128];
    __shared__ __align__(16) float bb_s[128];
    __shared__ __align__(16) float H1[EPI * HS];
    __shared__ __align__(16) float Pm[(K == 12) ? 16 * 128 : 4];

    int tid = threadIdx.x;
    {
        const float4* sb = (const float4*)WbTg;
        float4* db = (float4*)WbT;
        #pragma unroll
        for (int i = 0; i < 16; ++i) db[tid + i * NT] = sb[tid + i * NT];
        if (tid < 128) bb_s[tid] = bb[tid];
    }

    int b = blockIdx.x >> 7;
    int pbase = (blockIdx.x & 127) * 64;
    const int* idxb = idx + ((size_t)b * NPTS) * K;
    const float4* A4 = (const float4*)(A + ((size_t)b * NPTS) * 128);
    const float4* B4 = (const float4*)(Bm + ((size_t)b * NPTS) * 128);
    float* yb = y + ((size_t)b * NPTS) * 128;

    int og = tid & 15;        // 16 out-groups x 8 outputs
    int eg = tid >> 4;        // 16 edge-groups x TE edges
    int ebase = eg * TE;

    for (int it = 0; it < ITERS; ++it) {
        int pt0 = pbase + it * PI;
        #pragma unroll
        for (int r = 0; r < (EPI * 32) / NT; ++r) {
            int u = tid + r * NT;
            int e = u >> 5, c4 = u & 31;
            int p = pt0 + e / K;
            int j = idxb[(size_t)p * K + (e % K)];
            float4 av = A4[(size_t)j * 32 + c4];
            float4 bv = B4[(size_t)p * 32 + c4];
            *(float4*)&H1[e * HS + 4 * c4] = lrelu4(add4(av, bv));
        }
        __syncthreads();
        float4 acc[TE][2];
        {
            float4 blo = *(const float4*)&bb_s[og * 8];
            float4 bhi = *(const float4*)&bb_s[og * 8 + 4];
            #pragma unroll
            for (int e = 0; e < TE; ++e) { acc[e][0] = blo; acc[e][1] = bhi; }
        }
        #pragma unroll 2
        for (int c4 = 0; c4 < 32; ++c4) {
            float4 hv[TE];
            #pragma unroll
            for (int e = 0; e < TE; ++e)
                hv[e] = *(const float4*)&H1[(ebase + e) * HS + 4 * c4];
            #pragma unroll
            for (int j = 0; j < 4; ++j) {
                const float* wr = &WbT[(4 * c4 + j) * 128 + og * 8];
                float4 wlo = *(const float4*)wr;
                float4 whi = *(const float4*)(wr + 4);
                #pragma unroll
                for (int e = 0; e < TE; ++e) {
                    float hc = (j == 0) ? hv[e].x : (j == 1) ? hv[e].y : (j == 2) ? hv[e].z : hv[e].w;
                    acc[e][0].x += hc * wlo.x; acc[e][0].y += hc * wlo.y;
                    acc[e][0].z += hc * wlo.z; acc[e][0].w += hc * wlo.w;
                    acc[e][1].x += hc * whi.x; acc[e][1].y += hc * whi.y;
                    acc[e][1].z += hc * whi.z; acc[e][1].w += hc * whi.w;
                }
            }
        }
        float4 mlo = lrelu4(acc[0][0]), mhi = lrelu4(acc[0][1]);
        #pragma unroll
        for (int e = 1; e < TE; ++e) {
            mlo = fmax4(mlo, lrelu4(acc[e][0]));
            mhi = fmax4(mhi, lrelu4(acc[e][1]));
        }
        if constexpr (K == 4) {
            float4* yp = (float4*)&yb[((size_t)(pt0 + eg)) * 128 + og * 8];
            yp[0] = mlo; yp[1] = mhi;
            __syncthreads();
        } else {
            *(float4*)&Pm[eg * 128 + og * 8] = mlo;
            *(float4*)&Pm[eg * 128 + og * 8 + 4] = mhi;
            __syncthreads();
            #pragma unroll
            for (int r = 0; r < 4; ++r) {
                int u = tid + r * NT;
                int p = u >> 7, o = u & 127;
                yb[((size_t)(pt0 + p)) * 128 + o] =
                    fmaxf(Pm[(2 * p) * 128 + o], Pm[(2 * p + 1) * 128 + o]);
            }
        }
    }
}

// ---------------- conv_mid: y -> x1 fp32 + sq1 + bf16 h/m/l split ----------------
__global__ void k_conv_mid(const float* __restrict__ xin, const float* __restrict__ W,
                           const float* __restrict__ bias, float* __restrict__ out,
                           float* __restrict__ sq, unsigned short* __restrict__ xh,
                           unsigned short* __restrict__ xm, unsigned short* __restrict__ xl) {
    int gid = blockIdx.x * blockDim.x + threadIdx.x;
    const float4* row = (const float4*)(xin + (size_t)gid * 128);
    float acc[32];
    #pragma unroll
    for (int o = 0; o < 32; ++o) acc[o] = bias[o];
    #pragma unroll 2
    for (int c4 = 0; c4 < 32; ++c4) {
        float4 v = row[c4];
        #pragma unroll
        for (int o = 0; o < 32; ++o) {
            const float* w = W + o * 128 + c4 * 4;   // uniform -> s_load
            acc[o] += v.x * w[0] + v.y * w[1] + v.z * w[2] + v.w * w[3];
        }
    }
    float s = 0.f;
    float4* op = (float4*)(out + (size_t)gid * 32);
    unsigned int* hrow = (unsigned int*)(xh + (size_t)gid * 32);
    unsigned int* mrow = (unsigned int*)(xm + (size_t)gid * 32);
    unsigned int* lrow = (unsigned int*)(xl + (size_t)gid * 32);
    #pragma unroll
    for (int o4 = 0; o4 < 8; ++o4) {
        float4 v = make_float4(lrelu(acc[o4 * 4]), lrelu(acc[o4 * 4 + 1]),
                               lrelu(acc[o4 * 4 + 2]), lrelu(acc[o4 * 4 + 3]));
        s += v.x * v.x + v.y * v.y + v.z * v.z + v.w * v.w;
        op[o4] = v;
        unsigned int hp[2], mp[2], lp[2];
        split3(v, hp, mp, lp);
        *(uint2*)(hrow + o4 * 2) = make_uint2(hp[0], hp[1]);
        *(uint2*)(mrow + o4 * 2) = make_uint2(mp[0], mp[1]);
        *(uint2*)(lrow + o4 * 2) = make_uint2(lp[0], lp[1]);
    }
    sq[gid] = s;
}

// ---------------- decoder: y1 [B*N,128] -> out [B*N,12] ----------------
__global__ void k_decoder(const float* __restrict__ xin,
                          const float* __restrict__ W0, const float* __restrict__ b0,
                          const float* __restrict__ W1, const float* __restrict__ b1,
                          const float* __restrict__ W2, const float* __restrict__ b2,
                          float* __restrict__ out) {
    int gid = blockIdx.x * blockDim.x + threadIdx.x;
    const float4* row = (const float4*)(xin + (size_t)gid * 128);
    float h0[6];
    #pragma unroll
    for (int o = 0; o < 6; ++o) h0[o] = b0[o];
    #pragma unroll 4
    for (int c4 = 0; c4 < 32; ++c4) {
        float4 v = row[c4];
        #pragma unroll
        for (int o = 0; o < 6; ++o) {
            const float* w = W0 + o * 128 + c4 * 4;
            h0[o] += v.x * w[0] + v.y * w[1] + v.z * w[2] + v.w * w[3];
        }
    }
    #pragma unroll
    for (int o = 0; o < 6; ++o) h0[o] = lrelu(h0[o]);
    float h1[12];
    #pragma unroll
    for (int o = 0; o < 12; ++o) {
        float a = b1[o];
        #pragma unroll
        for (int j = 0; j < 6; ++j) a += W1[o * 6 + j] * h0[j];
        h1[o] = lrelu(a);
    }
    float* op = out + (size_t)gid * 12;
    #pragma unroll
    for (int o = 0; o < 12; ++o) {
        float a = b2[o];
        #pragma unroll
        for (int j = 0; j < 12; ++j) a += W2[o * 12 + j] * h1[j];
        op[o] = a;
    }
}

extern "C" void kernel_launch(void* const* d_in, const int* in_sizes, int n_in,
                              void* d_out, int out_size, void* d_ws, size_t ws_size,
                              hipStream_t stream) {
    const float* feature = (const float*)d_in[0];
    const float* Wc0 = (const float*)d_in[1];
    const float* bc0 = (const float*)d_in[2];
    const float* We0a = (const float*)d_in[3];
    const float* be0a = (const float*)d_in[4];
    const float* We0b = (const float*)d_in[5];
    const float* be0b = (const float*)d_in[6];
    const float* Wc1 = (const float*)d_in[7];
    const float* bc1 = (const float*)d_in[8];
    const float* We1a = (const float*)d_in[9];
    const float* be1a = (const float*)d_in[10];
    const float* We1b = (const float*)d_in[11];
    const float* be1b = (const float*)d_in[12];
    const float* Wd0 = (const float*)d_in[13];
    const float* bd0 = (const float*)d_in[14];
    const float* Wd1 = (const float*)d_in[15];
    const float* bd1 = (const float*)d_in[16];
    const float* Wd2 = (const float*)d_in[17];
    const float* bd2 = (const float*)d_in[18];
    float* out = (float*)d_out;

    float* f = (float*)d_ws;
    // layout (floats), total ~30.7 MB with phase-based aliasing (JS=16 variant)
    float* x0   = f;                       // [0, 524288)
    float* x1   = f + 524288;              // [524288, 1048576)
    int*   idx0 = (int*)(f + 1048576);     // 196608
    int*   idx1 = (int*)(f + 1245184);     // 65536
    float* wT   = f + 1310720;             // 32768 (WbT0 | WbT1)
    float* Zab  = f + 1343488;             // 4194304: A | Bm
    float* Abuf = Zab;                     // 2097152
    float* Bbuf = Zab + 2097152;           // 2097152
    float* Y    = f + 5537792;             // 2097152: y0, later y1
    float* sq0  = f + 7634944;             // 16384
    float* sq1  = f + 7651328;             // 16384 (end 7667712)
    // kNN0 (JS=16, K=12): splits live in x1+idx slots (dead then); c0 spans Zab+Y
    unsigned short* xh0 = (unsigned short*)(f + 524288);    // 262144 floats (x1 lo)
    unsigned short* xm0 = (unsigned short*)(f + 786432);    // 262144 floats (x1 hi)
    unsigned short* xl0 = (unsigned short*)(f + 1048576);   // 262144 floats (idx0+idx1 slots)
    float* c0d  = f + 1343488;             // 3145728 (Zab + part of range)
    int*   c0i  = (int*)(f + 4489216);     // 3145728, ends 7634944 (rest of Zab + Y)
    // kNN1 (JS=16, K=4): splits + cands all inside Zab (Abuf/Bbuf from block0 dead)
    unsigned short* xh1 = (unsigned short*)Zab;             // 262144 floats
    unsigned short* xm1 = (unsigned short*)(Zab + 262144);
    unsigned short* xl1 = (unsigned short*)(Zab + 524288);
    float* c1d  = Zab + 786432;            // 1048576
    int*   c1i  = (int*)(Zab + 1835008);   // 1048576, ends Zab+2883584 < 4194304
    float* WbT0 = wT;
    float* WbT1 = wT + 16384;

    k_transpose_w<<<128, 256, 0, stream>>>(We0b, We1b, wT);
    k_conv_in<<<64, 256, 0, stream>>>(feature, Wc0, bc0, x0, sq0, xh0, xm0, xl0);
    k_knn_mfma<12, 16, 10><<<2048, 128, 0, stream>>>(xh0, xm0, xl0, sq0, c0d, c0i);
    k_knn_merge<12, 16><<<256, 64, 0, stream>>>(c0d, c0i, idx0);
    k_premix<<<256, 256, 0, stream>>>(x0, We0a, be0a, Abuf, Bbuf);
    k_edgeconv4<12><<<256, 256, 0, stream>>>(idx0, Abuf, Bbuf, WbT0, be0b, Y);
    k_conv_mid<<<64, 256, 0, stream>>>(Y, Wc1, bc1, x1, sq1, xh1, xm1, xl1);
    k_knn_mfma<4, 16, 8><<<2048, 128, 0, stream>>>(xh1, xm1, xl1, sq1, c1d, c1i);
    k_knn_merge<4, 16><<<256, 64, 0, stream>>>(c1d, c1i, idx1);
    k_premix<<<256, 256, 0, stream>>>(x1, We1a, be1a, Abuf, Bbuf);
    k_edgeconv4<4><<<256, 256, 0, stream>>>(idx1, Abuf, Bbuf, WbT1, be1b, Y);
    k_decoder<<<64, 256, 0, stream>>>(Y, Wd0, bd0, Wd1, bd1, Wd2, bd2, out);
}

// Round 24
// 632.704 us; speedup vs baseline: 1.2501x; 1.2501x over previous
//
#include <hip/hip_runtime.h>

#define NPTS 8192
#define NB 2

typedef __attribute__((ext_vector_type(8))) short short8v;   // 8 bf16 (4 VGPRs)
typedef __attribute__((ext_vector_type(4))) float f32x4;

__device__ __forceinline__ float lrelu(float x) { return x > 0.f ? x : 0.2f * x; }
__device__ __forceinline__ float4 lrelu4(float4 a) {
    return make_float4(lrelu(a.x), lrelu(a.y), lrelu(a.z), lrelu(a.w));
}
__device__ __forceinline__ float4 fmax4(float4 a, float4 b) {
    return make_float4(fmaxf(a.x, b.x), fmaxf(a.y, b.y), fmaxf(a.z, b.z), fmaxf(a.w, b.w));
}
__device__ __forceinline__ float4 add4(float4 a, float4 b) {
    return make_float4(a.x + b.x, a.y + b.y, a.z + b.z, a.w + b.w);
}
__device__ __forceinline__ unsigned short f2bf(float f) {     // RNE bf16
    unsigned int u = __float_as_uint(f);
    return (unsigned short)((u + 0x7FFFu + ((u >> 16) & 1u)) >> 16);
}
__device__ __forceinline__ float bf2f(unsigned short h) {
    return __uint_as_float(((unsigned int)h) << 16);
}

// ---------------- prep: transpose layer-2 weights into ws (WbT[c][o]) ----------------
__global__ void k_transpose_w(const float* __restrict__ Wb0, const float* __restrict__ Wb1,
                              float* __restrict__ out) {
    int t = blockIdx.x * 256 + threadIdx.x;
    if (t < 16384)      out[t] = Wb0[(t & 127) * 128 + (t >> 7)];
    else if (t < 32768) { int i = t - 16384; out[t] = Wb1[(i & 127) * 128 + (i >> 7)]; }
}

// 3-way bf16 split of a float4, packed into 2 uints per level
__device__ __forceinline__ void split3(float4 v, unsigned int* hp, unsigned int* mp,
                                       unsigned int* lp) {
    float c[4] = {v.x, v.y, v.z, v.w};
    unsigned short h[4], m[4], l[4];
    #pragma unroll
    for (int i = 0; i < 4; ++i) {
        h[i] = f2bf(c[i]);
        float r1 = c[i] - bf2f(h[i]);
        m[i] = f2bf(r1);
        float r2 = r1 - bf2f(m[i]);
        l[i] = f2bf(r2);
    }
    hp[0] = (unsigned int)h[0] | ((unsigned int)h[1] << 16);
    hp[1] = (unsigned int)h[2] | ((unsigned int)h[3] << 16);
    mp[0] = (unsigned int)m[0] | ((unsigned int)m[1] << 16);
    mp[1] = (unsigned int)m[2] | ((unsigned int)m[3] << 16);
    lp[0] = (unsigned int)l[0] | ((unsigned int)l[1] << 16);
    lp[1] = (unsigned int)l[2] | ((unsigned int)l[3] << 16);
}

// ---------------- conv_in: feature -> x0 fp32 + sq0 + bf16 h/m/l split ----------------
__global__ void k_conv_in(const float* __restrict__ f, const float* __restrict__ W,
                          const float* __restrict__ bias, float* __restrict__ out,
                          float* __restrict__ sq, unsigned short* __restrict__ xh,
                          unsigned short* __restrict__ xm, unsigned short* __restrict__ xl) {
    int gid = blockIdx.x * blockDim.x + threadIdx.x;   // over B*N
    int b = gid >> 13, n = gid & (NPTS - 1);
    const float* fb = f + ((size_t)b << 20) + n;       // b*128*8192
    float acc[32];
    #pragma unroll
    for (int o = 0; o < 32; ++o) acc[o] = bias[o];
    #pragma unroll 4
    for (int c = 0; c < 128; ++c) {
        float xc = fb[(size_t)c * NPTS];               // coalesced across lanes
        #pragma unroll
        for (int o = 0; o < 32; ++o) acc[o] += xc * W[o * 128 + c];  // uniform -> s_load
    }
    float s = 0.f;
    float4* op = (float4*)(out + (size_t)gid * 32);
    unsigned int* hrow = (unsigned int*)(xh + (size_t)gid * 32);
    unsigned int* mrow = (unsigned int*)(xm + (size_t)gid * 32);
    unsigned int* lrow = (unsigned int*)(xl + (size_t)gid * 32);
    #pragma unroll
    for (int o4 = 0; o4 < 8; ++o4) {
        float4 v = make_float4(lrelu(acc[o4 * 4]), lrelu(acc[o4 * 4 + 1]),
                               lrelu(acc[o4 * 4 + 2]), lrelu(acc[o4 * 4 + 3]));
        s += v.x * v.x + v.y * v.y + v.z * v.z + v.w * v.w;
        op[o4] = v;
        unsigned int hp[2], mp[2], lp[2];
        split3(v, hp, mp, lp);
        *(uint2*)(hrow + o4 * 2) = make_uint2(hp[0], hp[1]);
        *(uint2*)(mrow + o4 * 2) = make_uint2(mp[0], mp[1]);
        *(uint2*)(lrow + o4 * 2) = make_uint2(lp[0], lp[1]);
    }
    sq[gid] = s;
}

// ---------------- premix: A = x @ Wa1^T ; Bm = x @ (Wa2-Wa1)^T + ba ----------------
// (256,2): 128-VGPR budget so xv[8]+acc[32] stay in registers (R19 fix).
__global__ __launch_bounds__(256, 2) void k_premix(const float* __restrict__ x,
                                                   const float* __restrict__ Wa,
                                                   const float* __restrict__ ba,
                                                   float* __restrict__ A,
                                                   float* __restrict__ Bm) {
    int tid = threadIdx.x;
    int q = tid >> 6;                       // quarter (wave-uniform)
    int p = blockIdx.x * 64 + (tid & 63);   // point over NB*NPTS
    float4 xv[8];
    {
        const float4* xr = (const float4*)(x + (size_t)p * 32);
        #pragma unroll
        for (int u = 0; u < 8; ++u) xv[u] = xr[u];
    }
    const float* W0 = Wa + q * 32 * 64;     // rows q*32..q*32+31
    float acc[32];
    #pragma unroll
    for (int o = 0; o < 32; ++o) acc[o] = 0.f;
    #pragma unroll 2
    for (int c4 = 0; c4 < 8; ++c4) {
        float4 v = xv[c4];
        #pragma unroll
        for (int o = 0; o < 32; ++o) {
            const float* w = W0 + o * 64 + c4 * 4;   // uniform -> s_load
            acc[o] += v.x * w[0] + v.y * w[1] + v.z * w[2] + v.w * w[3];
        }
    }
    {
        float4* op = (float4*)(A + (size_t)p * 128 + q * 32);
        #pragma unroll
        for (int o4 = 0; o4 < 8; ++o4)
            op[o4] = make_float4(acc[o4 * 4], acc[o4 * 4 + 1], acc[o4 * 4 + 2], acc[o4 * 4 + 3]);
    }
    #pragma unroll
    for (int o = 0; o < 32; ++o) acc[o] = ba[q * 32 + o];
    #pragma unroll 2
    for (int c4 = 0; c4 < 8; ++c4) {
        float4 v = xv[c4];
        #pragma unroll
        for (int o = 0; o < 32; ++o) {
            const float* w1 = W0 + o * 64 + c4 * 4;
            const float* w2 = w1 + 32;
            acc[o] += v.x * (w2[0] - w1[0]) + v.y * (w2[1] - w1[1]) +
                      v.z * (w2[2] - w1[2]) + v.w * (w2[3] - w1[3]);
        }
    }
    {
        float4* op = (float4*)(Bm + (size_t)p * 128 + q * 32);
        #pragma unroll
        for (int o4 = 0; o4 < 8; ++o4)
            op[o4] = make_float4(acc[o4 * 4], acc[o4 * 4 + 1], acc[o4 * 4 + 2], acc[o4 * 4 + 3]);
    }
}

// ---------------- kNN via MFMA Gram (bf16 3-way split, 6 terms), BARRIER-FREE ----------------
// JS=16: 2048 blocks -> high residency (total waves = points*JS/64; JS is the lever).
template <int K, int JS, int C>
__global__ __launch_bounds__(128, 2) void k_knn_mfma(const unsigned short* __restrict__ xh,
                                                     const unsigned short* __restrict__ xm,
                                                     const unsigned short* __restrict__ xl,
                                                     const float* __restrict__ sqg,
                                                     float* __restrict__ cand_d,
                                                     int* __restrict__ cand_i) {
    constexpr int IT = 128;                  // i-tile
    constexpr int JR = NPTS / JS;            // 512 for JS=16
    constexpr int NCH = JR / 16;             // chunks of 16 j
    constexpr int BPB = (NPTS / IT) * JS;    // blocks per batch
    constexpr int DS = 17;                   // Dl row stride (reads 2-way free)

    __shared__ float Dl[IT * DS];
    __shared__ float bufd[C * IT];           // transposed append buffer (conflict-free)
    __shared__ int   bufj[C * IT];

    int tid = threadIdx.x;
    int bid = blockIdx.x;
    int b = bid / BPB;
    int r0b = bid - b * BPB;
    int itile = r0b / JS;
    int jseg = r0b - itile * JS;

    const unsigned short* xhb = xh + ((size_t)b * NPTS) * 32;
    const unsigned short* xmb = xm + ((size_t)b * NPTS) * 32;
    const unsigned short* xlb = xl + ((size_t)b * NPTS) * 32;
    const float* sqb = sqg + (size_t)b * NPTS;

    int lane = tid & 63;
    int w = tid >> 6;          // wave 0..1 -> i rows [w*64, w*64+64)
    int g = lane >> 4;         // k-group: k = g*8 + e
    int r15 = lane & 15;

    // A fragments hoisted and pinned
    short8v ah[4], am[4], al[4];
    #pragma unroll
    for (int t = 0; t < 4; ++t) {
        size_t ii = (size_t)(itile * IT + w * 64 + t * 16 + r15);
        ah[t] = *(const short8v*)(xhb + ii * 32 + g * 8);
        am[t] = *(const short8v*)(xmb + ii * 32 + g * 8);
        al[t] = *(const short8v*)(xlb + ii * 32 + g * 8);
    }
    #pragma unroll
    for (int t = 0; t < 4; ++t) {
        asm volatile("" : "+v"(ah[t]));
        asm volatile("" : "+v"(am[t]));
        asm volatile("" : "+v"(al[t]));
    }

    float bd[K]; int bi[K];                  // sorted ascending, registers
    #pragma unroll
    for (int r = 0; r < K; ++r) { bd[r] = 1e30f; bi[r] = 0; }
    float thr = 1e30f;
    int cnt = 0;

    auto flush = [&]() {
        #pragma unroll
        for (int u = 0; u < C; ++u) {
            float dv = bufd[u * IT + tid];
            int jv = bufj[u * IT + tid];
            float dd = (u < cnt) ? dv : 1e30f;   // 1e30 never inserts (strict <)
            int ji = jv;
            #pragma unroll
            for (int r = 0; r < K; ++r) {
                bool c = dd < bd[r];
                float tf = bd[r]; int ti = bi[r];
                bd[r] = c ? dd : bd[r]; bi[r] = c ? ji : bi[r];
                dd = c ? tf : dd;       ji = c ? ti : ji;
            }
        }
        cnt = 0; thr = bd[K - 1];
    };

    int jbase = jseg * JR;
    #pragma unroll 1
    for (int ch = 0; ch < NCH; ++ch) {
        int j0 = jbase + ch * 16;
        // B fragments for this 16-j chunk (3 levels)
        short8v bh, bm, bl;
        {
            size_t ja = (size_t)(j0 + r15);
            bh = *(const short8v*)(xhb + ja * 32 + g * 8);
            bm = *(const short8v*)(xmb + ja * 32 + g * 8);
            bl = *(const short8v*)(xlb + ja * 32 + g * 8);
        }
        #pragma unroll
        for (int t = 0; t < 4; ++t) {
            f32x4 acc = {0.f, 0.f, 0.f, 0.f};
            acc = __builtin_amdgcn_mfma_f32_16x16x32_bf16(am[t], bm, acc, 0, 0, 0);
            acc = __builtin_amdgcn_mfma_f32_16x16x32_bf16(ah[t], bl, acc, 0, 0, 0);
            acc = __builtin_amdgcn_mfma_f32_16x16x32_bf16(al[t], bh, acc, 0, 0, 0);
            acc = __builtin_amdgcn_mfma_f32_16x16x32_bf16(ah[t], bm, acc, 0, 0, 0);
            acc = __builtin_amdgcn_mfma_f32_16x16x32_bf16(am[t], bh, acc, 0, 0, 0);
            acc = __builtin_amdgcn_mfma_f32_16x16x32_bf16(ah[t], bh, acc, 0, 0, 0);
            int il = w * 64 + t * 16 + g * 4;
            Dl[(il + 0) * DS + r15] = acc[0];
            Dl[(il + 1) * DS + r15] = acc[1];
            Dl[(il + 2) * DS + r15] = acc[2];
            Dl[(il + 3) * DS + r15] = acc[3];
        }
        // selection (wave-private Dl rows; intra-wave lgkmcnt ordering suffices).
        #pragma unroll 1
        for (int jq = 0; jq < 16; jq += 4) {
            float v0 = Dl[tid * DS + jq + 0];
            float v1 = Dl[tid * DS + jq + 1];
            float v2 = Dl[tid * DS + jq + 2];
            float v3 = Dl[tid * DS + jq + 3];
            int j = j0 + jq;
            float d0 = sqb[j + 0] - 2.f * v0;   // rank key (sq_i const offset per i)
            float d1 = sqb[j + 1] - 2.f * v1;
            float d2 = sqb[j + 2] - 2.f * v2;
            float d3 = sqb[j + 3] - 2.f * v3;
            // strict < : on distance tie the earlier (lower-index) j stays -> jax tie-break
            if (d0 < thr) { bufd[cnt * IT + tid] = d0; bufj[cnt * IT + tid] = j + 0; cnt++; }
            if (d1 < thr) { bufd[cnt * IT + tid] = d1; bufj[cnt * IT + tid] = j + 1; cnt++; }
            if (d2 < thr) { bufd[cnt * IT + tid] = d2; bufj[cnt * IT + tid] = j + 2; cnt++; }
            if (d3 < thr) { bufd[cnt * IT + tid] = d3; bufj[cnt * IT + tid] = j + 3; cnt++; }
            if (__any(cnt >= C - 3)) flush();   // capacity: cnt <= C-4 at group top
        }
    }
    flush();
    size_t base = ((size_t)jseg * (NB * NPTS) + (size_t)(b * NPTS) + itile * IT + tid) * K;
    #pragma unroll
    for (int r = 0; r < K; ++r) { cand_d[base + r] = bd[r]; cand_i[base + r] = bi[r]; }
}

// ---------------- merge v2: register insertion-chain with per-segment early exit ----------------
// Each segment list is sorted ascending (d, j); segments are ascending-j blocks.
// Inserting in (segment asc, within-segment asc) order with strict < reproduces
// the (d, j)-lexicographic top-K exactly. Early break: once d >= thr, the rest
// of the segment cannot insert (sorted; ties fail strict <).
template <int K, int JS>
__global__ __launch_bounds__(128, 4) void k_knn_merge2(const float* __restrict__ cand_d,
                                                       const int* __restrict__ cand_i,
                                                       int* __restrict__ idx_out) {
    int p = blockIdx.x * 128 + threadIdx.x;   // over NB*NPTS
    float bd[K]; int bi[K];
    #pragma unroll
    for (int r = 0; r < K; ++r) { bd[r] = 1e30f; bi[r] = 0; }
    float thr = 1e30f;
    #pragma unroll 1
    for (int s = 0; s < JS; ++s) {
        size_t base = ((size_t)s * (NB * NPTS) + p) * K;
        #pragma unroll 1
        for (int r = 0; r < K; ++r) {
            float d = cand_d[base + r];
            if (!(d < thr)) break;            // sorted: rest of segment can't insert
            int j = cand_i[base + r];
            float dd = d; int ji = j;
            #pragma unroll
            for (int q = 0; q < K; ++q) {
                bool c = dd < bd[q];
                float tf = bd[q]; int ti = bi[q];
                bd[q] = c ? dd : bd[q]; bi[q] = c ? ji : bi[q];
                dd = c ? tf : dd;       ji = c ? ti : ji;
            }
            thr = bd[K - 1];
        }
    }
    int* op = idx_out + (size_t)p * K;
    #pragma unroll
    for (int r = 0; r < K; ++r) op[r] = bi[r];
}

// ---------------- EdgeConv v4: register-lean 6x8 / 4x8 output tiles ----------------
template <int K>
__global__ __launch_bounds__(256, 1)
void k_edgeconv4(const int* __restrict__ idx,
                 const float* __restrict__ A, const float* __restrict__ Bm,
                 const float* __restrict__ WbTg, const float* __restrict__ bb,
                 float* __restrict__ y) {
    constexpr int TE = (K == 12) ? 6 : 4;     // edges per thread
    constexpr int EPI = 16 * TE;              // edges per iter: 96 / 64
    constexpr int PI = EPI / K;               // points per iter: 8 / 16
    constexpr int ITERS = 64 / PI;            // 8 / 4
    constexpr int NT = 256;
    constexpr int HS = 132;                   // H1 row stride

    __shared__ __align__(16) float WbT[128 * 128];
    __shared__ __align__(16) float bb_s[128];
    __shared__ __align__(16) float H1[EPI * HS];
    __shared__ __align__(16) float Pm[(K == 12) ? 16 * 128 : 4];

    int tid = threadIdx.x;
    {
        const float4* sb = (const float4*)WbTg;
        float4* db = (float4*)WbT;
        #pragma unroll
        for (int i = 0; i < 16; ++i) db[tid + i * NT] = sb[tid + i * NT];
        if (tid < 128) bb_s[tid] = bb[tid];
    }

    int b = blockIdx.x >> 7;
    int pbase = (blockIdx.x & 127) * 64;
    const int* idxb = idx + ((size_t)b * NPTS) * K;
    const float4* A4 = (const float4*)(A + ((size_t)b * NPTS) * 128);
    const float4* B4 = (const float4*)(Bm + ((size_t)b * NPTS) * 128);
    float* yb = y + ((size_t)b * NPTS) * 128;

    int og = tid & 15;        // 16 out-groups x 8 outputs
    int eg = tid >> 4;        // 16 edge-groups x TE edges
    int ebase = eg * TE;

    for (int it = 0; it < ITERS; ++it) {
        int pt0 = pbase + it * PI;
        #pragma unroll
        for (int r = 0; r < (EPI * 32) / NT; ++r) {
            int u = tid + r * NT;
            int e = u >> 5, c4 = u & 31;
            int p = pt0 + e / K;
            int j = idxb[(size_t)p * K + (e % K)];
            float4 av = A4[(size_t)j * 32 + c4];
            float4 bv = B4[(size_t)p * 32 + c4];
            *(float4*)&H1[e * HS + 4 * c4] = lrelu4(add4(av, bv));
        }
        __syncthreads();
        float4 acc[TE][2];
        {
            float4 blo = *(const float4*)&bb_s[og * 8];
            float4 bhi = *(const float4*)&bb_s[og * 8 + 4];
            #pragma unroll
            for (int e = 0; e < TE; ++e) { acc[e][0] = blo; acc[e][1] = bhi; }
        }
        #pragma unroll 2
        for (int c4 = 0; c4 < 32; ++c4) {
            float4 hv[TE];
            #pragma unroll
            for (int e = 0; e < TE; ++e)
                hv[e] = *(const float4*)&H1[(ebase + e) * HS + 4 * c4];
            #pragma unroll
            for (int j = 0; j < 4; ++j) {
                const float* wr = &WbT[(4 * c4 + j) * 128 + og * 8];
                float4 wlo = *(const float4*)wr;
                float4 whi = *(const float4*)(wr + 4);
                #pragma unroll
                for (int e = 0; e < TE; ++e) {
                    float hc = (j == 0) ? hv[e].x : (j == 1) ? hv[e].y : (j == 2) ? hv[e].z : hv[e].w;
                    acc[e][0].x += hc * wlo.x; acc[e][0].y += hc * wlo.y;
                    acc[e][0].z += hc * wlo.z; acc[e][0].w += hc * wlo.w;
                    acc[e][1].x += hc * whi.x; acc[e][1].y += hc * whi.y;
                    acc[e][1].z += hc * whi.z; acc[e][1].w += hc * whi.w;
                }
            }
        }
        float4 mlo = lrelu4(acc[0][0]), mhi = lrelu4(acc[0][1]);
        #pragma unroll
        for (int e = 1; e < TE; ++e) {
            mlo = fmax4(mlo, lrelu4(acc[e][0]));
            mhi = fmax4(mhi, lrelu4(acc[e][1]));
        }
        if constexpr (K == 4) {
            float4* yp = (float4*)&yb[((size_t)(pt0 + eg)) * 128 + og * 8];
            yp[0] = mlo; yp[1] = mhi;
            __syncthreads();
        } else {
            *(float4*)&Pm[eg * 128 + og * 8] = mlo;
            *(float4*)&Pm[eg * 128 + og * 8 + 4] = mhi;
            __syncthreads();
            #pragma unroll
            for (int r = 0; r < 4; ++r) {
                int u = tid + r * NT;
                int p = u >> 7, o = u & 127;
                yb[((size_t)(pt0 + p)) * 128 + o] =
                    fmaxf(Pm[(2 * p) * 128 + o], Pm[(2 * p + 1) * 128 + o]);
            }
        }
    }
}

// ---------------- conv_mid: y -> x1 fp32 + sq1 + bf16 h/m/l split ----------------
__global__ void k_conv_mid(const float* __restrict__ xin, const float* __restrict__ W,
                           const float* __restrict__ bias, float* __restrict__ out,
                           float* __restrict__ sq, unsigned short* __restrict__ xh,
                           unsigned short* __restrict__ xm, unsigned short* __restrict__ xl) {
    int gid = blockIdx.x * blockDim.x + threadIdx.x;
    const float4* row = (const float4*)(xin + (size_t)gid * 128);
    float acc[32];
    #pragma unroll
    for (int o = 0; o < 32; ++o) acc[o] = bias[o];
    #pragma unroll 2
    for (int c4 = 0; c4 < 32; ++c4) {
        float4 v = row[c4];
        #pragma unroll
        for (int o = 0; o < 32; ++o) {
            const float* w = W + o * 128 + c4 * 4;   // uniform -> s_load
            acc[o] += v.x * w[0] + v.y * w[1] + v.z * w[2] + v.w * w[3];
        }
    }
    float s = 0.f;
    float4* op = (float4*)(out + (size_t)gid * 32);
    unsigned int* hrow = (unsigned int*)(xh + (size_t)gid * 32);
    unsigned int* mrow = (unsigned int*)(xm + (size_t)gid * 32);
    unsigned int* lrow = (unsigned int*)(xl + (size_t)gid * 32);
    #pragma unroll
    for (int o4 = 0; o4 < 8; ++o4) {
        float4 v = make_float4(lrelu(acc[o4 * 4]), lrelu(acc[o4 * 4 + 1]),
                               lrelu(acc[o4 * 4 + 2]), lrelu(acc[o4 * 4 + 3]));
        s += v.x * v.x + v.y * v.y + v.z * v.z + v.w * v.w;
        op[o4] = v;
        unsigned int hp[2], mp[2], lp[2];
        split3(v, hp, mp, lp);
        *(uint2*)(hrow + o4 * 2) = make_uint2(hp[0], hp[1]);
        *(uint2*)(mrow + o4 * 2) = make_uint2(mp[0], mp[1]);
        *(uint2*)(lrow + o4 * 2) = make_uint2(lp[0], lp[1]);
    }
    sq[gid] = s;
}

// ---------------- decoder: y1 [B*N,128] -> out [B*N,12] ----------------
__global__ void k_decoder(const float* __restrict__ xin,
                          const float* __restrict__ W0, const float* __restrict__ b0,
                          const float* __restrict__ W1, const float* __restrict__ b1,
                          const float* __restrict__ W2, const float* __restrict__ b2,
                          float* __restrict__ out) {
    int gid = blockIdx.x * blockDim.x + threadIdx.x;
    const float4* row = (const float4*)(xin + (size_t)gid * 128);
    float h0[6];
    #pragma unroll
    for (int o = 0; o < 6; ++o) h0[o] = b0[o];
    #pragma unroll 4
    for (int c4 = 0; c4 < 32; ++c4) {
        float4 v = row[c4];
        #pragma unroll
        for (int o = 0; o < 6; ++o) {
            const float* w = W0 + o * 128 + c4 * 4;
            h0[o] += v.x * w[0] + v.y * w[1] + v.z * w[2] + v.w * w[3];
        }
    }
    #pragma unroll
    for (int o = 0; o < 6; ++o) h0[o] = lrelu(h0[o]);
    float h1[12];
    #pragma unroll
    for (int o = 0; o < 12; ++o) {
        float a = b1[o];
        #pragma unroll
        for (int j = 0; j < 6; ++j) a += W1[o * 6 + j] * h0[j];
        h1[o] = lrelu(a);
    }
    float* op = out + (size_t)gid * 12;
    #pragma unroll
    for (int o = 0; o < 12; ++o) {
        float a = b2[o];
        #pragma unroll
        for (int j = 0; j < 12; ++j) a += W2[o * 12 + j] * h1[j];
        op[o] = a;
    }
}

extern "C" void kernel_launch(void* const* d_in, const int* in_sizes, int n_in,
                              void* d_out, int out_size, void* d_ws, size_t ws_size,
                              hipStream_t stream) {
    const float* feature = (const float*)d_in[0];
    const float* Wc0 = (const float*)d_in[1];
    const float* bc0 = (const float*)d_in[2];
    const float* We0a = (const float*)d_in[3];
    const float* be0a = (const float*)d_in[4];
    const float* We0b = (const float*)d_in[5];
    const float* be0b = (const float*)d_in[6];
    const float* Wc1 = (const float*)d_in[7];
    const float* bc1 = (const float*)d_in[8];
    const float* We1a = (const float*)d_in[9];
    const float* be1a = (const float*)d_in[10];
    const float* We1b = (const float*)d_in[11];
    const float* be1b = (const float*)d_in[12];
    const float* Wd0 = (const float*)d_in[13];
    const float* bd0 = (const float*)d_in[14];
    const float* Wd1 = (const float*)d_in[15];
    const float* bd1 = (const float*)d_in[16];
    const float* Wd2 = (const float*)d_in[17];
    const float* bd2 = (const float*)d_in[18];
    float* out = (float*)d_out;

    float* f = (float*)d_ws;
    // layout (floats), total ~30.7 MB with phase-based aliasing (JS=16 variant)
    float* x0   = f;                       // [0, 524288)
    float* x1   = f + 524288;              // [524288, 1048576)
    int*   idx0 = (int*)(f + 1048576);     // 196608
    int*   idx1 = (int*)(f + 1245184);     // 65536
    float* wT   = f + 1310720;             // 32768 (WbT0 | WbT1)
    float* Zab  = f + 1343488;             // 4194304: A | Bm
    float* Abuf = Zab;                     // 2097152
    float* Bbuf = Zab + 2097152;           // 2097152
    float* Y    = f + 5537792;             // 2097152: y0, later y1
    float* sq0  = f + 7634944;             // 16384
    float* sq1  = f + 7651328;             // 16384 (end 7667712)
    // kNN0 (JS=16, K=12): splits live in x1+idx slots (dead then); c0 spans Zab+Y
    unsigned short* xh0 = (unsigned short*)(f + 524288);    // 262144 floats (x1 lo)
    unsigned short* xm0 = (unsigned short*)(f + 786432);    // 262144 floats (x1 hi)
    unsigned short* xl0 = (unsigned short*)(f + 1048576);   // 262144 floats (idx0+idx1 slots)
    float* c0d  = f + 1343488;             // 3145728 (Zab + part of range)
    int*   c0i  = (int*)(f + 4489216);     // 3145728, ends 7634944 (rest of Zab + Y)
    // kNN1 (JS=16, K=4): splits + cands all inside Zab (Abuf/Bbuf from block0 dead)
    unsigned short* xh1 = (unsigned short*)Zab;             // 262144 floats
    unsigned short* xm1 = (unsigned short*)(Zab + 262144);
    unsigned short* xl1 = (unsigned short*)(Zab + 524288);
    float* c1d  = Zab + 786432;            // 1048576
    int*   c1i  = (int*)(Zab + 1835008);   // 1048576, ends Zab+2883584 < 4194304
    float* WbT0 = wT;
    float* WbT1 = wT + 16384;

    k_transpose_w<<<128, 256, 0, stream>>>(We0b, We1b, wT);
    k_conv_in<<<64, 256, 0, stream>>>(feature, Wc0, bc0, x0, sq0, xh0, xm0, xl0);
    k_knn_mfma<12, 16, 10><<<2048, 128, 0, stream>>>(xh0, xm0, xl0, sq0, c0d, c0i);
    k_knn_merge2<12, 16><<<128, 128, 0, stream>>>(c0d, c0i, idx0);
    k_premix<<<256, 256, 0, stream>>>(x0, We0a, be0a, Abuf, Bbuf);
    k_edgeconv4<12><<<256, 256, 0, stream>>>(idx0, Abuf, Bbuf, WbT0, be0b, Y);
    k_conv_mid<<<64, 256, 0, stream>>>(Y, Wc1, bc1, x1, sq1, xh1, xm1, xl1);
    k_knn_mfma<4, 16, 8><<<2048, 128, 0, stream>>>(xh1, xm1, xl1, sq1, c1d, c1i);
    k_knn_merge2<4, 16><<<128, 128, 0, stream>>>(c1d, c1i, idx1);
    k_premix<<<256, 256, 0, stream>>>(x1, We1a, be1a, Abuf, Bbuf);
    k_edgeconv4<4><<<256, 256, 0, stream>>>(idx1, Abuf, Bbuf, WbT1, be1b, Y);
    k_decoder<<<64, 256, 0, stream>>>(Y, Wd0, bd0, Wd1, bd1, Wd2, bd2, out);
}